// Round 11
// baseline (132.963 us; speedup 1.0000x reference)
//
#include <hip/hip_runtime.h>
#include <stdint.h>
#include <stddef.h>

typedef __bf16 bf16x8 __attribute__((ext_vector_type(8)));
typedef float  f32x4  __attribute__((ext_vector_type(4)));
typedef unsigned u32x4 __attribute__((ext_vector_type(4)));

constexpr int BB  = 2;
constexpr int SS  = 2048;
constexpr int DD  = 1024;
constexpr int HH  = 16;
constexpr int DHD = 64;
constexpr int BHD = BB * HH;     // 32
constexpr int MTOK = BB * SS;    // 4096

__device__ __forceinline__ short f2bf(float f) {
  return (short)__builtin_bit_cast(unsigned short, (__bf16)f);
}
__device__ __forceinline__ uint32_t pk2bf(float a, float b) {
  uint32_t lo = __builtin_bit_cast(unsigned short, (__bf16)a);
  uint32_t hi = __builtin_bit_cast(unsigned short, (__bf16)b);
  return lo | (hi << 16);
}
__device__ __forceinline__ f32x4 mfma16(bf16x8 a, bf16x8 b, f32x4 c) {
  return __builtin_amdgcn_mfma_f32_16x16x32_bf16(a, b, c, 0, 0, 0);
}
__device__ __forceinline__ void gload16(const void* g, void* l) {
  __builtin_amdgcn_global_load_lds(
      (const __attribute__((address_space(1))) unsigned int*)g,
      (__attribute__((address_space(3))) unsigned int*)l, 16, 0, 0);
}

// ---------------------------------------------------------------------------
// Prepass: fp32 -> bf16 for q,k,v and the 4 weight matrices.
// ---------------------------------------------------------------------------
__global__ __launch_bounds__(256)
void cvt_kernel(const float* __restrict__ q, const float* __restrict__ k,
                const float* __restrict__ v,
                const float* __restrict__ wq, const float* __restrict__ wk,
                const float* __restrict__ wv, const float* __restrict__ wo,
                short* __restrict__ dq, short* __restrict__ dk,
                short* __restrict__ dv,
                short* __restrict__ dwq, short* __restrict__ dwk,
                short* __restrict__ dwv, short* __restrict__ dwo)
{
  constexpr int n4q = 1 << 20;
  constexpr int n4w = 1 << 18;
  constexpr int total = 3 * n4q + 4 * n4w;
  int i = blockIdx.x * 256 + threadIdx.x;
  for (; i < total; i += gridDim.x * 256) {
    const float* s; short* d; int off;
    if (i < 3 * n4q) {
      int sg = i >> 20; off = i & (n4q - 1);
      s = sg == 0 ? q : sg == 1 ? k : v;
      d = sg == 0 ? dq : sg == 1 ? dk : dv;
    } else {
      int j = i - 3 * n4q;
      int sg = j >> 18; off = j & (n4w - 1);
      s = sg == 0 ? wq : sg == 1 ? wk : sg == 2 ? wv : wo;
      d = sg == 0 ? dwq : sg == 1 ? dwk : sg == 2 ? dwv : dwo;
    }
    float4 x = ((const float4*)s)[off];
    uint2 o;
    o.x = pk2bf(x.x, x.y);
    o.y = pk2bf(x.z, x.w);
    ((uint2*)d)[off] = o;
  }
}

// ---------------------------------------------------------------------------
// m97-structure GEMM (r7 version, single-buffered - measured best):
// C = (A @ W^T + bias) * oscale. All-bf16, 128x128 tile, BK=32,
// global_load_lds width=16, linear LDS.
// ---------------------------------------------------------------------------
__device__ __forceinline__ void gemm_body(
    const short* __restrict__ A, const short* __restrict__ W,
    const float* __restrict__ bias, void* __restrict__ Cp,
    int mode, float oscale, int m0, int n0)
{
  __shared__ short As[128 * 32];
  __shared__ short Bs[128 * 32];
  const int t = threadIdx.x, lane = t & 63, w = t >> 6;
  const int wr = w >> 1, wc = w & 1, g = lane >> 4, l15 = lane & 15;

  f32x4 acc[4][4] = {};

  const int c0 = t, c1 = 256 + t;
  const short* ga0 = A + (size_t)(m0 + (c0 >> 2)) * 1024 + ((c0 & 3) << 3);
  const short* ga1 = A + (size_t)(m0 + (c1 >> 2)) * 1024 + ((c1 & 3) << 3);
  const short* gb0 = W + (size_t)(n0 + (c0 >> 2)) * 1024 + ((c0 & 3) << 3);
  const short* gb1 = W + (size_t)(n0 + (c1 >> 2)) * 1024 + ((c1 & 3) << 3);
  short* la0 = &As[(w * 64) * 8];
  short* la1 = &As[(256 + w * 64) * 8];
  short* lb0 = &Bs[(w * 64) * 8];
  short* lb1 = &Bs[(256 + w * 64) * 8];

  for (int k0 = 0; k0 < 1024; k0 += 32) {
    __syncthreads();
    gload16(ga0 + k0, la0);
    gload16(ga1 + k0, la1);
    gload16(gb0 + k0, lb0);
    gload16(gb1 + k0, lb1);
    __syncthreads();

    bf16x8 af[4], bfr[4];
    #pragma unroll
    for (int m = 0; m < 4; ++m)
      af[m] = *(const bf16x8*)&As[(wr * 64 + m * 16 + l15) * 32 + g * 8];
    #pragma unroll
    for (int n = 0; n < 4; ++n)
      bfr[n] = *(const bf16x8*)&Bs[(wc * 64 + n * 16 + l15) * 32 + g * 8];
    #pragma unroll
    for (int m = 0; m < 4; ++m)
      #pragma unroll
      for (int n = 0; n < 4; ++n)
        acc[m][n] = mfma16(af[m], bfr[n], acc[m][n]);
  }

  // C/D: col = lane&15, row = (lane>>4)*4 + reg  [m89]
  #pragma unroll
  for (int n = 0; n < 4; ++n) {
    int ng = n0 + wc * 64 + n * 16 + l15;
    float bv = bias[ng];
    #pragma unroll
    for (int m = 0; m < 4; ++m) {
      int mb = m0 + wr * 64 + m * 16 + g * 4;
      #pragma unroll
      for (int r = 0; r < 4; ++r) {
        int mg = mb + r;
        float val = (acc[m][n][r] + bv) * oscale;
        if (mode == 1) {
          ((float*)Cp)[(size_t)mg * 1024 + ng] = val;
        } else {
          int b = mg >> 11, srow = mg & 2047;
          int h = ng >> 6,  dh   = ng & 63;
          if (mode == 0)
            ((short*)Cp)[(((size_t)b * HH + h) * SS + srow) * DHD + dh] = f2bf(val);
          else
            ((short*)Cp)[(((size_t)b * HH + h) * DHD + dh) * SS + srow] = f2bf(val);
        }
      }
    }
  }
}

constexpr float QSCALE = 0.18033688011112042f;  // 0.125 * log2(e)

__global__ __launch_bounds__(256)
void qkv_kernel(const short* __restrict__ qb, const short* __restrict__ kb,
                const short* __restrict__ vb,
                const short* __restrict__ wq16, const short* __restrict__ wk16,
                const short* __restrict__ wv16,
                const float* __restrict__ bq, const float* __restrict__ bk,
                const float* __restrict__ bv,
                short* __restrict__ qh, short* __restrict__ kh,
                short* __restrict__ vt)
{
  const int z = blockIdx.z;
  const short* A = (z == 0) ? qb : (z == 1) ? kb : vb;
  const short* W = (z == 0) ? wq16 : (z == 1) ? wk16 : wv16;
  const float* b = (z == 0) ? bq : (z == 1) ? bk : bv;
  void* C = (z == 0) ? (void*)qh : (z == 1) ? (void*)kh : (void*)vt;
  int mode = (z == 2) ? 2 : 0;
  float sc = (z == 0) ? QSCALE : 1.0f;
  gemm_body(A, W, b, C, mode, sc, blockIdx.x * 128, blockIdx.y * 128);
}

__global__ __launch_bounds__(256)
void proj_kernel(const short* __restrict__ ao, const short* __restrict__ wo16,
                 const float* __restrict__ bo, float* __restrict__ out)
{
  gemm_body(ao, wo16, bo, out, 1, 1.0f, blockIdx.x * 128, blockIdx.y * 128);
}

// ---------------------------------------------------------------------------
// Flash attention v11: 32 q-rows per wave (2 q16-blocks), 128 q per block,
// KVBLK=128, 512 blocks. Inner loop per 32-kv block: 4 K ds_reads feed
// 8 QK MFMAs (both q-blocks), each V ds_read feeds 2 PV MFMAs ->
// MFMA:ds_read = 2:1 (r10 was 1:1; LDS traffic per unit work halved).
// Wave-uniform skip of fully-masked 32-kv blocks in the diagonal tile.
// r10-verified pieces: swizzled staging, T14 issue/commit, permlane
// P-transpose, no-max exp2 softmax, LPT + XCD head affinity, T5 setprio.
// ---------------------------------------------------------------------------
__global__ __launch_bounds__(256)
void attn_kernel(const short* __restrict__ qh, const short* __restrict__ kh,
                 const short* __restrict__ vt, short* __restrict__ out)
{
  __shared__ short Ks[128 * 64];     // [kv=128][d=64], swz byte^=(row&7)<<4
  __shared__ short Vs[64 * 128];     // [d=64][kv=128], swz byte^=(row&15)<<4

  const int wg = blockIdx.x;
  const int s  = wg >> 3;
  const int bh = (wg & 7) * 4 + (s & 3);      // 4 heads per XCD
  const int y  = 15 - (s >> 2);               // 128-row q-tile, LPT order
  const int ktiles = y + 1;                   // 128-wide kv tiles

  const int t = threadIdx.x, lane = t & 63, w = t >> 6;
  const int g = lane >> 4, l15 = lane & 15;

  // Q fragments: qf[qb][kk], col q = y*128 + w*32 + qb*16 + l15
  bf16x8 qf[2][2];
  #pragma unroll
  for (int qb2 = 0; qb2 < 2; ++qb2) {
    const short* qp =
        qh + ((size_t)bh * SS + y * 128 + w * 32 + qb2 * 16 + l15) * DHD + g * 8;
    qf[qb2][0] = *(const bf16x8*)(qp);
    qf[qb2][1] = *(const bf16x8*)(qp + 32);
  }

  f32x4 o[2][4] = {};                 // [qb][nd]
  f32x4 lv[2] = {};                   // row-sum partials (q = qb*16+l15)

  const short* kbh = kh + (size_t)bh * SS * DHD;
  const short* vbh = vt + (size_t)bh * DHD * SS;

  bf16x8 kr[4], vr[4];
  auto issue = [&](int k0) {
    #pragma unroll
    for (int j = 0; j < 4; ++j) {
      int c = j * 256 + t;
      kr[j] = *(const bf16x8*)(kbh + (size_t)(k0 + (c >> 3)) * DHD + ((c & 7) << 3));
      vr[j] = *(const bf16x8*)(vbh + (size_t)(c >> 4) * SS + k0 + ((c & 15) << 3));
    }
  };
  auto commit = [&]() {
    #pragma unroll
    for (int j = 0; j < 4; ++j) {
      int c = j * 256 + t;
      int kb_ = ((c >> 3) * 128 + (c & 7) * 16) ^ (((c >> 3) & 7) << 4);
      int vb_ = ((c >> 4) * 256 + (c & 15) * 16) ^ (((c >> 4) & 15) << 4);
      *(bf16x8*)((char*)Ks + kb_) = kr[j];
      *(bf16x8*)((char*)Vs + vb_) = vr[j];
    }
  };

  issue(0);
  for (int kt = 0; kt < ktiles; ++kt) {
    const int k0 = kt * 128;
    const bool lastt = (kt == ktiles - 1);
    __syncthreads();                  // prev compute done, buffers free
    commit();                         // vmcnt wait + swizzled ds_write
    __syncthreads();                  // tile staged
    if (!lastt) issue(k0 + 128);      // next tile flies under compute

    #pragma unroll
    for (int i = 0; i < 4; ++i) {     // 32-kv block i
      // wave-uniform liveness vs diagonal (q_max(qb) = w*32 + qb*16 + 15)
      bool live1 = !lastt || (32 * i <= w * 32 + 31);
      if (!live1) break;              // later i are dead too
      bool live0 = !lastt || (32 * i <= w * 32 + 15);

      // ---- 4 K ds_reads, shared by both q-blocks ----
      int row0 = 32 * i + l15;
      int sw = (row0 & 7) << 4;       // (row0+16)&7 == row0&7
      const char* kbase = (const char*)Ks;
      bf16x8 k00 = *(const bf16x8*)(kbase + ((row0 * 128 + g * 16) ^ sw));
      bf16x8 k01 = *(const bf16x8*)(kbase + ((row0 * 128 + 64 + g * 16) ^ sw));
      bf16x8 k10 = *(const bf16x8*)(kbase + (((row0 + 16) * 128 + g * 16) ^ sw));
      bf16x8 k11 = *(const bf16x8*)(kbase + (((row0 + 16) * 128 + 64 + g * 16) ^ sw));

      // ---- QK + softmax + transpose per q-block ----
      bf16x8 pa[2];
      #pragma unroll
      for (int qb2 = 0; qb2 < 2; ++qb2) {
        if (qb2 == 0 && !live0) { continue; }
        f32x4 z0 = {0.f, 0.f, 0.f, 0.f}, z1 = {0.f, 0.f, 0.f, 0.f};
        __builtin_amdgcn_s_setprio(1);
        z0 = mfma16(k00, qf[qb2][0], z0);
        z0 = mfma16(k01, qf[qb2][1], z0);
        z1 = mfma16(k10, qf[qb2][0], z1);
        z1 = mfma16(k11, qf[qb2][1], z1);
        __builtin_amdgcn_s_setprio(0);
        if (lastt) {
          int qg = y * 128 + w * 32 + qb2 * 16 + l15;
          int kvb = k0 + 32 * i + g * 4;
          #pragma unroll
          for (int r = 0; r < 4; ++r) {
            if (kvb + r      > qg) z0[r] = -__builtin_inff();
            if (kvb + 16 + r > qg) z1[r] = -__builtin_inff();
          }
        }
        #pragma unroll
        for (int r = 0; r < 4; ++r) {
          z0[r] = exp2f(z0[r]);
          z1[r] = exp2f(z1[r]);
        }
        lv[qb2] += z0;
        lv[qb2] += z1;
        // in-register transpose to PV A-operand (kv = g*8+j) [r8-verified]
        uint32_t w0 = pk2bf(z0[0], z0[1]);
        uint32_t w1 = pk2bf(z0[2], z0[3]);
        uint32_t w2 = pk2bf(z1[0], z1[1]);
        uint32_t w3 = pk2bf(z1[2], z1[3]);
        auto p1 = __builtin_amdgcn_permlane32_swap(w0, w2, false, false);
        auto p2 = __builtin_amdgcn_permlane16_swap(p1[0], p1[1], false, false);
        auto p3 = __builtin_amdgcn_permlane32_swap(w1, w3, false, false);
        auto p4 = __builtin_amdgcn_permlane16_swap(p3[0], p3[1], false, false);
        u32x4 paw = {(unsigned)p2[0], (unsigned)p4[0],
                     (unsigned)p2[1], (unsigned)p4[1]};
        pa[qb2] = __builtin_bit_cast(bf16x8, paw);
      }

      // ---- PV: each V ds_read feeds both q-blocks ----
      __builtin_amdgcn_s_setprio(1);
      #pragma unroll
      for (int nd = 0; nd < 4; ++nd) {
        int row = nd * 16 + l15;
        int byt = (row * 256 + i * 64 + g * 16) ^ ((row & 15) << 4);
        bf16x8 vf = *(const bf16x8*)((const char*)Vs + byt);
        if (live0) o[0][nd] = mfma16(pa[0], vf, o[0][nd]);
        o[1][nd] = mfma16(pa[1], vf, o[1][nd]);
      }
      __builtin_amdgcn_s_setprio(0);
    }
  }

  // ---- epilogue: reduce l, normalize, write [B,S,D] bf16 ----
  const int b = bh >> 4, h = bh & 15;
  #pragma unroll
  for (int qb2 = 0; qb2 < 2; ++qb2) {
    float l = (lv[qb2][0] + lv[qb2][1]) + (lv[qb2][2] + lv[qb2][3]);
    l += __shfl_xor(l, 16, 64);
    l += __shfl_xor(l, 32, 64);
    #pragma unroll
    for (int r = 0; r < 4; ++r) {
      float lr = __shfl(l, g * 4 + r, 64);  // lane g*4+r holds q-row g*4+r sum
      float inv = 1.0f / lr;
      int srow = y * 128 + w * 32 + qb2 * 16 + g * 4 + r;
      #pragma unroll
      for (int nd = 0; nd < 4; ++nd) {
        int dcol = h * 64 + nd * 16 + l15;
        out[((size_t)b * SS + srow) * DD + dcol] = f2bf(o[qb2][nd][r] * inv);
      }
    }
  }
}

// ---------------------------------------------------------------------------
extern "C" void kernel_launch(void* const* d_in, const int* in_sizes, int n_in,
                              void* d_out, int out_size, void* d_ws, size_t ws_size,
                              hipStream_t stream) {
  (void)in_sizes; (void)n_in; (void)out_size; (void)ws_size;
  const float* q  = (const float*)d_in[0];
  const float* k  = (const float*)d_in[1];
  const float* v  = (const float*)d_in[2];
  // d_in[3] = causal mask (statically triu(k=1)) applied analytically
  const float* Wq = (const float*)d_in[4];
  const float* bq = (const float*)d_in[5];
  const float* Wk = (const float*)d_in[6];
  const float* bk = (const float*)d_in[7];
  const float* Wv = (const float*)d_in[8];
  const float* bv = (const float*)d_in[9];
  const float* Wo = (const float*)d_in[10];
  const float* bo = (const float*)d_in[11];

  constexpr size_t NTOK = (size_t)MTOK * DD;
  constexpr size_t NW   = (size_t)DD * DD;
  short* qb16 = (short*)d_ws;
  short* kb16 = qb16 + NTOK;
  short* vb16 = kb16 + NTOK;
  short* wq16 = vb16 + NTOK;
  short* wk16 = wq16 + NW;
  short* wv16 = wk16 + NW;
  short* wo16 = wv16 + NW;
  short* qh   = wo16 + NW;                       // [B,H,S,DH] bf16 (pre-scaled)
  short* kh   = qh + NTOK;                       // [B,H,S,DH] bf16
  short* vt   = kh + NTOK;                       // [B,H,DH,S] bf16
  short* ao   = qb16;                            // aliases qb16 (dead by then)

  dim3 blk(256);
  cvt_kernel<<<dim3(2048), blk, 0, stream>>>(q, k, v, Wq, Wk, Wv, Wo,
                                             qb16, kb16, vb16,
                                             wq16, wk16, wv16, wo16);
  qkv_kernel<<<dim3(MTOK / 128, DD / 128, 3), blk, 0, stream>>>(
      qb16, kb16, vb16, wq16, wk16, wv16, bq, bk, bv, qh, kh, vt);
  attn_kernel<<<dim3(512), blk, 0, stream>>>(qh, kh, vt, ao);
  proj_kernel<<<dim3(MTOK / 128, DD / 128), blk, 0, stream>>>(ao, wo16, bo,
                                                              (float*)d_out);
}

// Round 12
// 130.015 us; speedup vs baseline: 1.0227x; 1.0227x over previous
//
#include <hip/hip_runtime.h>
#include <stdint.h>
#include <stddef.h>

typedef __bf16 bf16x8 __attribute__((ext_vector_type(8)));
typedef float  f32x4  __attribute__((ext_vector_type(4)));
typedef unsigned u32x4 __attribute__((ext_vector_type(4)));

constexpr int BB  = 2;
constexpr int SS  = 2048;
constexpr int DD  = 1024;
constexpr int HH  = 16;
constexpr int DHD = 64;
constexpr int BHD = BB * HH;     // 32
constexpr int MTOK = BB * SS;    // 4096

__device__ __forceinline__ short f2bf(float f) {
  return (short)__builtin_bit_cast(unsigned short, (__bf16)f);
}
__device__ __forceinline__ uint32_t pk2bf(float a, float b) {
  uint32_t lo = __builtin_bit_cast(unsigned short, (__bf16)a);
  uint32_t hi = __builtin_bit_cast(unsigned short, (__bf16)b);
  return lo | (hi << 16);
}
__device__ __forceinline__ f32x4 mfma16(bf16x8 a, bf16x8 b, f32x4 c) {
  return __builtin_amdgcn_mfma_f32_16x16x32_bf16(a, b, c, 0, 0, 0);
}
__device__ __forceinline__ void gload16(const void* g, void* l) {
  __builtin_amdgcn_global_load_lds(
      (const __attribute__((address_space(1))) unsigned int*)g,
      (__attribute__((address_space(3))) unsigned int*)l, 16, 0, 0);
}

// ---------------------------------------------------------------------------
// Prepass: fp32 -> bf16 for q,k,v and the 4 weight matrices.
// ---------------------------------------------------------------------------
__global__ __launch_bounds__(256)
void cvt_kernel(const float* __restrict__ q, const float* __restrict__ k,
                const float* __restrict__ v,
                const float* __restrict__ wq, const float* __restrict__ wk,
                const float* __restrict__ wv, const float* __restrict__ wo,
                short* __restrict__ dq, short* __restrict__ dk,
                short* __restrict__ dv,
                short* __restrict__ dwq, short* __restrict__ dwk,
                short* __restrict__ dwv, short* __restrict__ dwo)
{
  constexpr int n4q = 1 << 20;
  constexpr int n4w = 1 << 18;
  constexpr int total = 3 * n4q + 4 * n4w;
  int i = blockIdx.x * 256 + threadIdx.x;
  for (; i < total; i += gridDim.x * 256) {
    const float* s; short* d; int off;
    if (i < 3 * n4q) {
      int sg = i >> 20; off = i & (n4q - 1);
      s = sg == 0 ? q : sg == 1 ? k : v;
      d = sg == 0 ? dq : sg == 1 ? dk : dv;
    } else {
      int j = i - 3 * n4q;
      int sg = j >> 18; off = j & (n4w - 1);
      s = sg == 0 ? wq : sg == 1 ? wk : sg == 2 ? wv : wo;
      d = sg == 0 ? dwq : sg == 1 ? dwk : sg == 2 ? dwv : dwo;
    }
    float4 x = ((const float4*)s)[off];
    uint2 o;
    o.x = pk2bf(x.x, x.y);
    o.y = pk2bf(x.z, x.w);
    ((uint2*)d)[off] = o;
  }
}

// ---------------------------------------------------------------------------
// m97-structure GEMM (single-buffered - measured best):
// C = (A @ W^T + bias) * oscale. All-bf16, 128x128 tile, BK=32,
// global_load_lds width=16, linear LDS.
// ---------------------------------------------------------------------------
__device__ __forceinline__ void gemm_body(
    const short* __restrict__ A, const short* __restrict__ W,
    const float* __restrict__ bias, void* __restrict__ Cp,
    int mode, float oscale, int m0, int n0)
{
  __shared__ short As[128 * 32];
  __shared__ short Bs[128 * 32];
  const int t = threadIdx.x, lane = t & 63, w = t >> 6;
  const int wr = w >> 1, wc = w & 1, g = lane >> 4, l15 = lane & 15;

  f32x4 acc[4][4] = {};

  const int c0 = t, c1 = 256 + t;
  const short* ga0 = A + (size_t)(m0 + (c0 >> 2)) * 1024 + ((c0 & 3) << 3);
  const short* ga1 = A + (size_t)(m0 + (c1 >> 2)) * 1024 + ((c1 & 3) << 3);
  const short* gb0 = W + (size_t)(n0 + (c0 >> 2)) * 1024 + ((c0 & 3) << 3);
  const short* gb1 = W + (size_t)(n0 + (c1 >> 2)) * 1024 + ((c1 & 3) << 3);
  short* la0 = &As[(w * 64) * 8];
  short* la1 = &As[(256 + w * 64) * 8];
  short* lb0 = &Bs[(w * 64) * 8];
  short* lb1 = &Bs[(256 + w * 64) * 8];

  for (int k0 = 0; k0 < 1024; k0 += 32) {
    __syncthreads();
    gload16(ga0 + k0, la0);
    gload16(ga1 + k0, la1);
    gload16(gb0 + k0, lb0);
    gload16(gb1 + k0, lb1);
    __syncthreads();

    bf16x8 af[4], bfr[4];
    #pragma unroll
    for (int m = 0; m < 4; ++m)
      af[m] = *(const bf16x8*)&As[(wr * 64 + m * 16 + l15) * 32 + g * 8];
    #pragma unroll
    for (int n = 0; n < 4; ++n)
      bfr[n] = *(const bf16x8*)&Bs[(wc * 64 + n * 16 + l15) * 32 + g * 8];
    #pragma unroll
    for (int m = 0; m < 4; ++m)
      #pragma unroll
      for (int n = 0; n < 4; ++n)
        acc[m][n] = mfma16(af[m], bfr[n], acc[m][n]);
  }

  // C/D: col = lane&15, row = (lane>>4)*4 + reg  [m89]
  #pragma unroll
  for (int n = 0; n < 4; ++n) {
    int ng = n0 + wc * 64 + n * 16 + l15;
    float bv = bias[ng];
    #pragma unroll
    for (int m = 0; m < 4; ++m) {
      int mb = m0 + wr * 64 + m * 16 + g * 4;
      #pragma unroll
      for (int r = 0; r < 4; ++r) {
        int mg = mb + r;
        float val = (acc[m][n][r] + bv) * oscale;
        if (mode == 1) {
          ((float*)Cp)[(size_t)mg * 1024 + ng] = val;
        } else {
          int b = mg >> 11, srow = mg & 2047;
          int h = ng >> 6,  dh   = ng & 63;
          if (mode == 0)
            ((short*)Cp)[(((size_t)b * HH + h) * SS + srow) * DHD + dh] = f2bf(val);
          else
            ((short*)Cp)[(((size_t)b * HH + h) * DHD + dh) * SS + srow] = f2bf(val);
        }
      }
    }
  }
}

constexpr float QSCALE = 0.18033688011112042f;  // 0.125 * log2(e)

__global__ __launch_bounds__(256)
void qkv_kernel(const short* __restrict__ qb, const short* __restrict__ kb,
                const short* __restrict__ vb,
                const short* __restrict__ wq16, const short* __restrict__ wk16,
                const short* __restrict__ wv16,
                const float* __restrict__ bq, const float* __restrict__ bk,
                const float* __restrict__ bv,
                short* __restrict__ qh, short* __restrict__ kh,
                short* __restrict__ vt)
{
  const int z = blockIdx.z;
  const short* A = (z == 0) ? qb : (z == 1) ? kb : vb;
  const short* W = (z == 0) ? wq16 : (z == 1) ? wk16 : wv16;
  const float* b = (z == 0) ? bq : (z == 1) ? bk : bv;
  void* C = (z == 0) ? (void*)qh : (z == 1) ? (void*)kh : (void*)vt;
  int mode = (z == 2) ? 2 : 0;
  float sc = (z == 0) ? QSCALE : 1.0f;
  gemm_body(A, W, b, C, mode, sc, blockIdx.x * 128, blockIdx.y * 128);
}

__global__ __launch_bounds__(256)
void proj_kernel(const short* __restrict__ ao, const short* __restrict__ wo16,
                 const float* __restrict__ bo, float* __restrict__ out)
{
  gemm_body(ao, wo16, bo, out, 1, 1.0f, blockIdx.x * 128, blockIdx.y * 128);
}

// ---------------------------------------------------------------------------
// Flash attention v12: r10 shell (1024 blocks, 64q x KVBLK=128, LPT + XCD
// affinity, swizzled staging, T14 issue/commit, no-max exp2 softmax,
// permlane P-transpose) with QUADRANT waves: wave w=(wq,wk) computes
// q rows wq*32+[0,32) x kv wk*64+[0,64). Each K ds_read feeds 2 q-blocks,
// each V ds_read feeds 2 PV MFMAs -> block LDS reads HALVED (64/tile vs
// r10's 128) at identical MFMA count. kv split across waves -> pure-sum
// partials combined in the r8-verified bf16-LDS epilogue (reuses staging
// LDS; footprint stays 32KB). Wave-uniform diagonal skip of dead kv-halves.
// ---------------------------------------------------------------------------
__global__ __launch_bounds__(256)
void attn_kernel(const short* __restrict__ qh, const short* __restrict__ kh,
                 const short* __restrict__ vt, short* __restrict__ out)
{
  __shared__ char smem[32 * 1024];
  short* Ks = (short*)smem;             // [kv=128][d=64], swz byte^=(row&7)<<4
  short* Vs = (short*)(smem + 16384);   // [d=64][kv=128], swz byte^=(row&15)<<4

  const int wg = blockIdx.x;
  const int s  = wg >> 3;
  const int bh = (wg & 7) * 4 + (s & 3);      // 4 heads per XCD
  const int y  = 31 - (s >> 2);               // 64-row q-tile, LPT order
  const int ktiles = (y + 2) >> 1;            // 128-wide kv tiles

  const int t = threadIdx.x, lane = t & 63, w = t >> 6;
  const int wq = w >> 1, wk = w & 1;
  const int g = lane >> 4, l15 = lane & 15;

  // Q fragments: qf[qb][kk], col q = y*64 + wq*32 + qb*16 + l15
  bf16x8 qf[2][2];
  #pragma unroll
  for (int qb2 = 0; qb2 < 2; ++qb2) {
    const short* qp =
        qh + ((size_t)bh * SS + y * 64 + wq * 32 + qb2 * 16 + l15) * DHD + g * 8;
    qf[qb2][0] = *(const bf16x8*)(qp);
    qf[qb2][1] = *(const bf16x8*)(qp + 32);
  }

  f32x4 o[2][4] = {};                 // [qb][nd]
  f32x4 lv2[2] = {};                  // kv-half partial row-sums (q=qb*16+l15)

  const short* kbh = kh + (size_t)bh * SS * DHD;
  const short* vbh = vt + (size_t)bh * DHD * SS;

  bf16x8 kr[4], vr[4];
  auto issue = [&](int k0) {
    #pragma unroll
    for (int j = 0; j < 4; ++j) {
      int c = j * 256 + t;
      kr[j] = *(const bf16x8*)(kbh + (size_t)(k0 + (c >> 3)) * DHD + ((c & 7) << 3));
      vr[j] = *(const bf16x8*)(vbh + (size_t)(c >> 4) * SS + k0 + ((c & 15) << 3));
    }
  };
  auto commit = [&]() {
    #pragma unroll
    for (int j = 0; j < 4; ++j) {
      int c = j * 256 + t;
      int kb_ = ((c >> 3) * 128 + (c & 7) * 16) ^ (((c >> 3) & 7) << 4);
      int vb_ = ((c >> 4) * 256 + (c & 15) * 16) ^ (((c >> 4) & 15) << 4);
      *(bf16x8*)((char*)Ks + kb_) = kr[j];
      *(bf16x8*)((char*)Vs + vb_) = vr[j];
    }
  };

  const int qmaxw = y * 64 + wq * 32;          // wave's q base
  issue(0);
  for (int kt = 0; kt < ktiles; ++kt) {
    const int k0 = kt * 128;
    const bool lastt = (kt == ktiles - 1);
    __syncthreads();                  // prev compute done, buffers free
    commit();                         // vmcnt wait + swizzled ds_write
    __syncthreads();                  // tile staged
    if (!lastt) issue(k0 + 128);      // next tile flies under compute

    // wave-uniform: skip if this wave's kv-half is fully above its q rows
    if (lastt && (k0 + wk * 64) > qmaxw + 31) continue;

    #pragma unroll
    for (int i = 0; i < 2; ++i) {     // 32-kv block within the wave's half
      const int kvloc = wk * 64 + i * 32;
      const bool live1 = !lastt || (k0 + kvloc) <= qmaxw + 31;
      if (!live1) continue;
      const bool live0 = !lastt || (k0 + kvloc) <= qmaxw + 15;

      // ---- 4 K ds_reads, shared by both q-blocks ----
      int row0 = kvloc + l15;
      int sw = (row0 & 7) << 4;       // rows row0, row0+16 share the swizzle
      const char* kbase = (const char*)Ks;
      bf16x8 k00 = *(const bf16x8*)(kbase + ((row0 * 128 + g * 16) ^ sw));
      bf16x8 k01 = *(const bf16x8*)(kbase + ((row0 * 128 + 64 + g * 16) ^ sw));
      bf16x8 k10 = *(const bf16x8*)(kbase + (((row0 + 16) * 128 + g * 16) ^ sw));
      bf16x8 k11 = *(const bf16x8*)(kbase + (((row0 + 16) * 128 + 64 + g * 16) ^ sw));

      // ---- QK + exp2 + in-register transpose per q-block [r11-verified] ----
      bf16x8 pa[2];
      #pragma unroll
      for (int qb2 = 0; qb2 < 2; ++qb2) {
        if (qb2 == 0 && !live0) continue;
        f32x4 z0 = {0.f, 0.f, 0.f, 0.f}, z1 = {0.f, 0.f, 0.f, 0.f};
        __builtin_amdgcn_s_setprio(1);
        z0 = mfma16(k00, qf[qb2][0], z0);
        z0 = mfma16(k01, qf[qb2][1], z0);
        z1 = mfma16(k10, qf[qb2][0], z1);
        z1 = mfma16(k11, qf[qb2][1], z1);
        __builtin_amdgcn_s_setprio(0);
        if (lastt) {
          int qg = qmaxw + qb2 * 16 + l15;
          int kvb = k0 + kvloc + g * 4;
          #pragma unroll
          for (int r = 0; r < 4; ++r) {
            if (kvb + r      > qg) z0[r] = -__builtin_inff();
            if (kvb + 16 + r > qg) z1[r] = -__builtin_inff();
          }
        }
        #pragma unroll
        for (int r = 0; r < 4; ++r) {
          z0[r] = exp2f(z0[r]);
          z1[r] = exp2f(z1[r]);
        }
        lv2[qb2] += z0;
        lv2[qb2] += z1;
        uint32_t w0 = pk2bf(z0[0], z0[1]);
        uint32_t w1 = pk2bf(z0[2], z0[3]);
        uint32_t w2 = pk2bf(z1[0], z1[1]);
        uint32_t w3 = pk2bf(z1[2], z1[3]);
        auto p1 = __builtin_amdgcn_permlane32_swap(w0, w2, false, false);
        auto p2 = __builtin_amdgcn_permlane16_swap(p1[0], p1[1], false, false);
        auto p3 = __builtin_amdgcn_permlane32_swap(w1, w3, false, false);
        auto p4 = __builtin_amdgcn_permlane16_swap(p3[0], p3[1], false, false);
        u32x4 paw = {(unsigned)p2[0], (unsigned)p4[0],
                     (unsigned)p2[1], (unsigned)p4[1]};
        pa[qb2] = __builtin_bit_cast(bf16x8, paw);
      }

      // ---- PV: each V ds_read feeds both q-blocks ----
      __builtin_amdgcn_s_setprio(1);
      #pragma unroll
      for (int nd = 0; nd < 4; ++nd) {
        int row = nd * 16 + l15;
        int byt = (row * 256 + kvloc * 2 + g * 16) ^ ((row & 15) << 4);
        bf16x8 vf = *(const bf16x8*)((const char*)Vs + byt);
        if (live0) o[0][nd] = mfma16(pa[0], vf, o[0][nd]);
        o[1][nd] = mfma16(pa[1], vf, o[1][nd]);
      }
      __builtin_amdgcn_s_setprio(0);
    }
  }

  // ---- epilogue: 2-way kv-half combine (r8-verified pattern) ----
  __syncthreads();                    // all tile reads done; reuse smem
  short* osum = (short*)smem;         // [4 w][32 q][68 d] bf16, 17.4 KB
  float* lsumA = (float*)(smem + 4 * 32 * 68 * 2);  // [4 w][32 q]
  #pragma unroll
  for (int qb2 = 0; qb2 < 2; ++qb2) {
    float lp = (lv2[qb2][0] + lv2[qb2][1]) + (lv2[qb2][2] + lv2[qb2][3]);
    lp += __shfl_xor(lp, 16, 64);
    lp += __shfl_xor(lp, 32, 64);
    if (g == 0) lsumA[w * 32 + qb2 * 16 + l15] = lp;
    #pragma unroll
    for (int nd = 0; nd < 4; ++nd)
      #pragma unroll
      for (int r = 0; r < 4; ++r)
        osum[(w * 32 + qb2 * 16 + g * 4 + r) * 68 + nd * 16 + l15] =
            f2bf(o[qb2][nd][r]);
  }
  __syncthreads();

  const int qrow = t >> 2, c4 = t & 3;        // 64 rows x 4 threads/row
  const int wq2 = qrow >> 5, rloc = qrow & 31;
  float lt = lsumA[(wq2 * 2 + 0) * 32 + rloc] + lsumA[(wq2 * 2 + 1) * 32 + rloc];
  float inv = 1.0f / lt;
  float acc[16] = {};
  #pragma unroll
  for (int pp = 0; pp < 2; ++pp) {
    const uint2* src =
        (const uint2*)&osum[((wq2 * 2 + pp) * 32 + rloc) * 68 + c4 * 16];
    #pragma unroll
    for (int u = 0; u < 4; ++u) {
      uint2 dpair = src[u];
      acc[4 * u + 0] += __builtin_bit_cast(float, dpair.x << 16);
      acc[4 * u + 1] += __builtin_bit_cast(float, dpair.x & 0xffff0000u);
      acc[4 * u + 2] += __builtin_bit_cast(float, dpair.y << 16);
      acc[4 * u + 3] += __builtin_bit_cast(float, dpair.y & 0xffff0000u);
    }
  }
  const int b = bh >> 4, h = bh & 15;
  int srow = y * 64 + qrow;
  int dcol = h * 64 + c4 * 16;
  short* op = out + ((size_t)b * SS + srow) * DD + dcol;
  u32x4 ow0 = {pk2bf(acc[0] * inv, acc[1] * inv), pk2bf(acc[2] * inv, acc[3] * inv),
               pk2bf(acc[4] * inv, acc[5] * inv), pk2bf(acc[6] * inv, acc[7] * inv)};
  u32x4 ow1 = {pk2bf(acc[8] * inv, acc[9] * inv), pk2bf(acc[10] * inv, acc[11] * inv),
               pk2bf(acc[12] * inv, acc[13] * inv), pk2bf(acc[14] * inv, acc[15] * inv)};
  *(u32x4*)(op)     = ow0;
  *(u32x4*)(op + 8) = ow1;
}

// ---------------------------------------------------------------------------
extern "C" void kernel_launch(void* const* d_in, const int* in_sizes, int n_in,
                              void* d_out, int out_size, void* d_ws, size_t ws_size,
                              hipStream_t stream) {
  (void)in_sizes; (void)n_in; (void)out_size; (void)ws_size;
  const float* q  = (const float*)d_in[0];
  const float* k  = (const float*)d_in[1];
  const float* v  = (const float*)d_in[2];
  // d_in[3] = causal mask (statically triu(k=1)) applied analytically
  const float* Wq = (const float*)d_in[4];
  const float* bq = (const float*)d_in[5];
  const float* Wk = (const float*)d_in[6];
  const float* bk = (const float*)d_in[7];
  const float* Wv = (const float*)d_in[8];
  const float* bv = (const float*)d_in[9];
  const float* Wo = (const float*)d_in[10];
  const float* bo = (const float*)d_in[11];

  constexpr size_t NTOK = (size_t)MTOK * DD;
  constexpr size_t NW   = (size_t)DD * DD;
  short* qb16 = (short*)d_ws;
  short* kb16 = qb16 + NTOK;
  short* vb16 = kb16 + NTOK;
  short* wq16 = vb16 + NTOK;
  short* wk16 = wq16 + NW;
  short* wv16 = wk16 + NW;
  short* wo16 = wv16 + NW;
  short* qh   = wo16 + NW;                       // [B,H,S,DH] bf16 (pre-scaled)
  short* kh   = qh + NTOK;                       // [B,H,S,DH] bf16
  short* vt   = kh + NTOK;                       // [B,H,DH,S] bf16
  short* ao   = qb16;                            // aliases qb16 (dead by then)

  dim3 blk(256);
  cvt_kernel<<<dim3(2048), blk, 0, stream>>>(q, k, v, Wq, Wk, Wv, Wo,
                                             qb16, kb16, vb16,
                                             wq16, wk16, wv16, wo16);
  qkv_kernel<<<dim3(MTOK / 128, DD / 128, 3), blk, 0, stream>>>(
      qb16, kb16, vb16, wq16, wk16, wv16, bq, bk, bv, qh, kh, vt);
  attn_kernel<<<dim3(1024), blk, 0, stream>>>(qh, kh, vt, ao);
  proj_kernel<<<dim3(MTOK / 128, DD / 128), blk, 0, stream>>>(ao, wo16, bo,
                                                              (float*)d_out);
}